// Round 3
// baseline (1006.029 us; speedup 1.0000x reference)
//
#include <hip/hip_runtime.h>
#include <hip/hip_bf16.h>

// Problem constants (reference: B=2048, D=256, N=65536)
#define BB 2048
#define DD 256
#define NN 65536
#define TEMP_INV 20.0f   // 1 / 0.05
#define MOM 0.2f
#define OMM 0.8f

typedef __attribute__((ext_vector_type(8))) short bf16x8_t;
typedef __attribute__((ext_vector_type(4))) float f32x4_t;

// ---------------------------------------------------------------------------
// Kernel 1: row-normalize inputs -> xn (fp32) and xn_bf16. One wave per row.
// ---------------------------------------------------------------------------
__global__ void norm_kernel(const float* __restrict__ inp,
                            float* __restrict__ xn,
                            ushort* __restrict__ xnb) {
    int wid  = (int)((blockIdx.x * blockDim.x + threadIdx.x) >> 6);
    int lane = threadIdx.x & 63;
    if (wid >= BB) return;
    float4 v = reinterpret_cast<const float4*>(inp + (size_t)wid * DD)[lane];
    float ss = v.x * v.x + v.y * v.y + v.z * v.z + v.w * v.w;
    #pragma unroll
    for (int m = 32; m; m >>= 1) ss += __shfl_xor(ss, m);
    float s = 1.0f / fmaxf(sqrtf(ss), 1e-12f);
    v.x *= s; v.y *= s; v.z *= s; v.w *= s;
    reinterpret_cast<float4*>(xn + (size_t)wid * DD)[lane] = v;
    union { ushort4 u; __hip_bfloat16 h[4]; } cv;
    cv.h[0] = __float2bfloat16(v.x);
    cv.h[1] = __float2bfloat16(v.y);
    cv.h[2] = __float2bfloat16(v.z);
    cv.h[3] = __float2bfloat16(v.w);
    reinterpret_cast<ushort4*>(xnb)[(size_t)wid * (DD / 4) + lane] = cv.u;
}

// ---------------------------------------------------------------------------
// Kernel 2: GEMM  out[m][n] = (sum_k xn[m][k] * feat[n][k]) * 20
// bf16 MFMA 16x16x32, 128x128 tile, 4 waves of 64x64, BK=64, padded LDS.
// ---------------------------------------------------------------------------
#define BM 128
#define BN 128
#define BK 64
#define LDK 72   // padded LDS row length (bf16): 144 B row stride = 9*16 B

__global__ __launch_bounds__(256, 2)
void gemm_kernel(const ushort* __restrict__ Abf,   // xn bf16 [BB][DD]
                 const float*  __restrict__ Feat,  // features fp32 [NN][DD]
                 float* __restrict__ Out)          // [BB][NN]
{
    __shared__ ushort As[BM][LDK];
    __shared__ ushort Bs[BN][LDK];

    // XCD-aware swizzle: nwg = 16*512 = 8192, divisible by 8.
    const int nwg = (BB / BM) * (NN / BN);
    const int cpx = nwg >> 3;
    int bid = (int)blockIdx.x;
    int swz = (bid & 7) * cpx + (bid >> 3);
    int bm = swz & 15;   // M-tile fastest: 16 consecutive blocks share B-panel
    int bn = swz >> 4;

    const int tid  = threadIdx.x;
    const int lane = tid & 63;
    const int wid  = tid >> 6;       // 0..3
    const int wr   = wid >> 1;       // wave row (0..1)
    const int wc   = wid & 1;        // wave col (0..1)

    const int m0 = bm * BM;
    const int n0 = bn * BN;

    f32x4_t acc[4][4];
    #pragma unroll
    for (int i = 0; i < 4; ++i)
        #pragma unroll
        for (int j = 0; j < 4; ++j)
            acc[i][j] = (f32x4_t){0.f, 0.f, 0.f, 0.f};

    for (int kt = 0; kt < DD; kt += BK) {
        __syncthreads();   // previous tile fully consumed
        // ---- stage A: 128x64 bf16 (16 KB), 1024 chunks of 8 bf16 ----
        #pragma unroll
        for (int it = 0; it < 4; ++it) {
            int chunk = it * 256 + tid;          // 0..1023
            int row = chunk >> 3;                // /8 chunks per row
            int kc  = (chunk & 7) * 8;
            bf16x8_t v = *reinterpret_cast<const bf16x8_t*>(
                Abf + (size_t)(m0 + row) * DD + kt + kc);
            *reinterpret_cast<bf16x8_t*>(&As[row][kc]) = v;
        }
        // ---- stage B: 128x64 fp32 -> bf16 convert ----
        #pragma unroll
        for (int it = 0; it < 8; ++it) {
            int chunk = it * 256 + tid;          // 0..2047
            int row = chunk >> 4;                // /16 chunks per row
            int kc  = (chunk & 15) * 4;
            float4 v = *reinterpret_cast<const float4*>(
                Feat + (size_t)(n0 + row) * DD + kt + kc);
            union { ushort4 u; __hip_bfloat16 h[4]; } cv;
            cv.h[0] = __float2bfloat16(v.x);
            cv.h[1] = __float2bfloat16(v.y);
            cv.h[2] = __float2bfloat16(v.z);
            cv.h[3] = __float2bfloat16(v.w);
            *reinterpret_cast<ushort4*>(&Bs[row][kc]) = cv.u;
        }
        __syncthreads();
        // ---- compute: 2 k-steps of 32, 16 MFMA each ----
        #pragma unroll
        for (int kk = 0; kk < BK; kk += 32) {
            const int kb = kk + (lane >> 4) * 8;
            const int ar = wr * 64 + (lane & 15);
            const int br = wc * 64 + (lane & 15);
            bf16x8_t af[4], bfr[4];
            #pragma unroll
            for (int i = 0; i < 4; ++i) {
                af[i]  = *reinterpret_cast<const bf16x8_t*>(&As[ar + i * 16][kb]);
                bfr[i] = *reinterpret_cast<const bf16x8_t*>(&Bs[br + i * 16][kb]);
            }
            #pragma unroll
            for (int i = 0; i < 4; ++i)
                #pragma unroll
                for (int j = 0; j < 4; ++j)
                    acc[i][j] = __builtin_amdgcn_mfma_f32_16x16x32_bf16(
                        af[i], bfr[j], acc[i][j], 0, 0, 0);
        }
    }

    // ---- epilogue: scale by 1/TEMP and store ----
    // C/D mapping (m89-verified): col = lane&15, row = (lane>>4)*4 + reg
    #pragma unroll
    for (int i = 0; i < 4; ++i) {
        int rbase = m0 + wr * 64 + i * 16 + (lane >> 4) * 4;
        #pragma unroll
        for (int j = 0; j < 4; ++j) {
            int c = n0 + wc * 64 + j * 16 + (lane & 15);
            #pragma unroll
            for (int v = 0; v < 4; ++v) {
                Out[(size_t)(rbase + v) * NN + c] = acc[i][j][v] * TEMP_INV;
            }
        }
    }
}

// ---------------------------------------------------------------------------
// Kernel 3: copy features -> out_features (updated rows overwritten later)
// ---------------------------------------------------------------------------
__global__ void copy_kernel(const float* __restrict__ src, float* __restrict__ dst) {
    size_t n4 = (size_t)NN * DD / 4;
    size_t stride = (size_t)gridDim.x * blockDim.x;
    for (size_t i = blockIdx.x * blockDim.x + threadIdx.x; i < n4; i += stride) {
        reinterpret_cast<float4*>(dst)[i] = reinterpret_cast<const float4*>(src)[i];
    }
}

// ---------------------------------------------------------------------------
// Kernel 4: sequential momentum-EMA scatter, order-correct for duplicates.
// One wave per batch index; only the first occurrence's wave processes the
// target, applying all occurrences in batch order.
// ---------------------------------------------------------------------------
__global__ void update_kernel(const int* __restrict__ tgt,
                              const float* __restrict__ feat,
                              const float* __restrict__ xn,
                              float* __restrict__ outF) {
    __shared__ int t[BB];   // 8 KB
    for (int i = threadIdx.x; i < BB; i += blockDim.x) t[i] = tgt[i];
    __syncthreads();

    int wid  = (int)((blockIdx.x * blockDim.x + threadIdx.x) >> 6);
    int lane = threadIdx.x & 63;
    if (wid >= BB) return;
    int y = t[wid];
    // leader check: any earlier occurrence of y?  (wave-uniform loop)
    for (int j = 0; j < wid; ++j)
        if (t[j] == y) return;

    float4 f = reinterpret_cast<const float4*>(feat + (size_t)y * DD)[lane];
    for (int j = wid; j < BB; ++j) {
        if (t[j] != y) continue;
        float4 x = reinterpret_cast<const float4*>(xn + (size_t)j * DD)[lane];
        f.x = MOM * f.x + OMM * x.x;
        f.y = MOM * f.y + OMM * x.y;
        f.z = MOM * f.z + OMM * x.z;
        f.w = MOM * f.w + OMM * x.w;
        float ss = f.x * f.x + f.y * f.y + f.z * f.z + f.w * f.w;
        #pragma unroll
        for (int m = 32; m; m >>= 1) ss += __shfl_xor(ss, m);
        float inv = 1.0f / sqrtf(ss);
        f.x *= inv; f.y *= inv; f.z *= inv; f.w *= inv;
    }
    reinterpret_cast<float4*>(outF + (size_t)y * DD)[lane] = f;
}

// ---------------------------------------------------------------------------
extern "C" void kernel_launch(void* const* d_in, const int* in_sizes, int n_in,
                              void* d_out, int out_size, void* d_ws, size_t ws_size,
                              hipStream_t stream) {
    const float* inputs   = (const float*)d_in[0];
    const int*   targets  = (const int*)d_in[1];
    const float* features = (const float*)d_in[2];

    float* out  = (float*)d_out;                      // [BB*NN] outputs
    float* outF = out + (size_t)BB * NN;              // [NN*DD] new_features

    float*  xn  = (float*)d_ws;                                   // 2 MB
    ushort* xnb = (ushort*)((char*)d_ws + (size_t)BB * DD * 4);   // 1 MB

    norm_kernel<<<BB / 4, 256, 0, stream>>>(inputs, xn, xnb);
    gemm_kernel<<<(BB / BM) * (NN / BN), 256, 0, stream>>>(xnb, features, out);
    copy_kernel<<<2048, 256, 0, stream>>>(features, outF);
    update_kernel<<<BB / 4, 256, 0, stream>>>(targets, features, xn, outF);
}